// Round 8
// baseline (7585.013 us; speedup 1.0000x reference)
//
#include <hip/hip_runtime.h>

#define NT 16384
#define DM 4096
#define NE 64
#define TOPK 8
#define BTOK 64            // tokens per block
#define CHK 128            // K-chunk staged per iteration
#define NCHK (DM / CHK)    // 32
#define LSTR 132           // padded LDS row stride (floats): b128 reads at bank floor
#define NEGINF (-3.402823466e38f)

#define FOR_8(A) A(0) A(1) A(2) A(3) A(4) A(5) A(6) A(7)

__global__ __launch_bounds__(512, 2) void gate_kernel(
    const float* __restrict__ x,
    const float* __restrict__ W,
    int* __restrict__ out) {

  __shared__ float lds[2][BTOK][LSTR];   // 2 x 64 x 132 x 4B = 67.6 KB

  const int t     = threadIdx.x;
  const int lane  = t & 63;
  const int wid   = t >> 6;      // expert group 0..7
  const int ebase = wid * 8;

  // staging geometry: thread t covers row t/8, float4 columns (t&7)+8j, j=0..3
  // -> per-instruction global access is dense 128B runs per row (coalesced)
  const int srow = t >> 3;
  const int scol = (t & 7) << 2; // float offset of j=0
  const float* xg = x + (size_t)(blockIdx.x * BTOK + srow) * DM + scol;
  float* sdst = &lds[0][0][0] + srow * LSTR + scol;

#define STAGE_LOAD(c) { \
  const float* _g = xg + (c) * CHK; \
  g0 = *(const float4*)(_g);      g1 = *(const float4*)(_g + 32); \
  g2 = *(const float4*)(_g + 64); g3 = *(const float4*)(_g + 96); }

#define STAGE_WRITE(b) { \
  float* _d = sdst + (b) * (BTOK * LSTR); \
  *(float4*)(_d)      = g0; *(float4*)(_d + 32) = g1; \
  *(float4*)(_d + 64) = g2; *(float4*)(_d + 96) = g3; }

#define DECL_ACC(e) float acc##e = 0.f;
  FOR_8(DECL_ACC)

  // 16-wide dot window: x from LDS regs (xv0..3), W wave-uniform (1 line/instr)
#define DOT8(e) { \
  const float* _w = wb + (size_t)(e) * DM; \
  const float4 w0 = *(const float4*)(_w); \
  const float4 w1 = *(const float4*)(_w + 4); \
  const float4 w2 = *(const float4*)(_w + 8); \
  const float4 w3 = *(const float4*)(_w + 12); \
  float s; \
  s = xv0.x * w0.x;         s = fmaf(xv0.y, w0.y, s); \
  s = fmaf(xv0.z, w0.z, s); s = fmaf(xv0.w, w0.w, s); \
  s = fmaf(xv1.x, w1.x, s); s = fmaf(xv1.y, w1.y, s); \
  s = fmaf(xv1.z, w1.z, s); s = fmaf(xv1.w, w1.w, s); \
  s = fmaf(xv2.x, w2.x, s); s = fmaf(xv2.y, w2.y, s); \
  s = fmaf(xv2.z, w2.z, s); s = fmaf(xv2.w, w2.w, s); \
  s = fmaf(xv3.x, w3.x, s); s = fmaf(xv3.y, w3.y, s); \
  s = fmaf(xv3.z, w3.z, s); s = fmaf(xv3.w, w3.w, s); \
  acc##e += s; }

  float4 g0, g1, g2, g3;
  STAGE_LOAD(0)
  STAGE_WRITE(0)
  STAGE_LOAD(1)            // prefetch chunk 1 into regs; written after barrier
  __syncthreads();         // buf0 ready

  const float* xls = &lds[0][0][0] + lane * LSTR;  // lane's token row

  for (int c = 0; c < NCHK; ++c) {
    const int cur = c & 1;
    const float* xc   = xls + cur * (BTOK * LSTR);
    const float* wrow = W + (size_t)ebase * DM + c * CHK;
#pragma unroll
    for (int sw = 0; sw < 8; ++sw) {
      const float* _x = xc + sw * 16;
      const float4 xv0 = *(const float4*)(_x);
      const float4 xv1 = *(const float4*)(_x + 4);
      const float4 xv2 = *(const float4*)(_x + 8);
      const float4 xv3 = *(const float4*)(_x + 12);
      const float* wb = wrow + sw * 16;
      FOR_8(DOT8)
    }
    if (c + 1 < NCHK) {
      __syncthreads();               // everyone done reading the stale buffer
      STAGE_WRITE(cur ^ 1)           // commit chunk c+1
      if (c + 2 < NCHK) STAGE_LOAD(c + 2)  // start chunk c+2 loads
      __syncthreads();               // chunk c+1 visible
    }
  }

  // ---- logits into buf0: row = token(lane), col = expert ----
  {
    float* _d = &lds[0][lane][ebase];   // 16B-aligned (132*lane + 8*wid ≡ 0 mod 4)
    *(float4*)(_d)     = make_float4(acc0, acc1, acc2, acc3);
    *(float4*)(_d + 4) = make_float4(acc4, acc5, acc6, acc7);
  }
  __syncthreads();

  // ---- top-8: wave wid handles tokens wid*8..wid*8+7; lane = expert ----
  // wave-max butterfly + ballot; lowest set bit = lowest expert index (stable)
#define PICK(p) { \
  float m = v; \
  m = fmaxf(m, __shfl_xor(m, 32)); \
  m = fmaxf(m, __shfl_xor(m, 16)); \
  m = fmaxf(m, __shfl_xor(m, 8));  \
  m = fmaxf(m, __shfl_xor(m, 4));  \
  m = fmaxf(m, __shfl_xor(m, 2));  \
  m = fmaxf(m, __shfl_xor(m, 1));  \
  const unsigned long long bm = __ballot(v == m); \
  const int ii = (int)__builtin_ctzll(bm); \
  idx##p = ii; \
  v = (lane == ii) ? NEGINF : v; }

  for (int tt = 0; tt < 8; ++tt) {
    const int trow = wid * 8 + tt;
    float v = lds[0][trow][lane];
    int idx0, idx1, idx2, idx3, idx4, idx5, idx6, idx7;
    PICK(0) PICK(1) PICK(2) PICK(3) PICK(4) PICK(5) PICK(6) PICK(7)
    if (lane == 0) {
      int4* op = (int4*)(out + (size_t)(blockIdx.x * BTOK + trow) * TOPK);
      op[0] = make_int4(idx0, idx1, idx2, idx3);
      op[1] = make_int4(idx4, idx5, idx6, idx7);
    }
  }
}

extern "C" void kernel_launch(void* const* d_in, const int* in_sizes, int n_in,
                              void* d_out, int out_size, void* d_ws, size_t ws_size,
                              hipStream_t stream) {
  const float* x = (const float*)d_in[0];
  const float* W = (const float*)d_in[1];
  int* out = (int*)d_out;
  (void)in_sizes; (void)n_in; (void)out_size; (void)d_ws; (void)ws_size;

  dim3 grid(NT / BTOK);  // 256 blocks, one per 64 tokens (~1 per CU)
  dim3 block(512);       // 8 waves x 8 experts
  hipLaunchKernelGGL(gate_kernel, grid, block, 0, stream, x, W, out);
}

// Round 9
// 190.405 us; speedup vs baseline: 39.8362x; 39.8362x over previous
//
#include <hip/hip_runtime.h>

typedef short short8 __attribute__((ext_vector_type(8)));
typedef float f32x16 __attribute__((ext_vector_type(16)));

#define NT 16384
#define DM 4096
#define NE 64
#define TOPK 8
#define BTOK 32            // tokens per block
#define BK 32              // K per chunk
#define NCHK (DM / BK)     // 128
#define STR 40             // LDS row stride in bf16 elems (80 B): uniform bank load
#define LSTRF 68           // logits row stride (floats)
#define NEGINF (-3.402823466e38f)

#define MFMA(a, b, c) __builtin_amdgcn_mfma_f32_32x32x16_bf16((a), (b), (c), 0, 0, 0)

__device__ inline unsigned short bf16rne(float v) {       // RNE fp32->bf16 bits
  unsigned int u = __float_as_uint(v);
  unsigned int r = u + 0x7FFFu + ((u >> 16) & 1u);
  return (unsigned short)(r >> 16);
}
__device__ inline float bf16val(unsigned short b) {
  return __uint_as_float(((unsigned int)b) << 16);
}

// v = h + m*2^-8 + l*2^-16 + rho, |rho| <= 2^-25|v|  (exact subtractions)
#define SPLIT(v, H, M, L) { \
  const float _v = (v); \
  const unsigned short _hb = bf16rne(_v); \
  const float _s1 = (_v - bf16val(_hb)) * 256.0f; \
  const unsigned short _mb = bf16rne(_s1); \
  const float _s2 = (_s1 - bf16val(_mb)) * 256.0f; \
  const unsigned short _lb = bf16rne(_s2); \
  H = (short)_hb; M = (short)_mb; L = (short)_lb; }

__global__ __launch_bounds__(128) void gate_kernel(
    const float* __restrict__ x,
    const float* __restrict__ W,
    int* __restrict__ out) {

  __shared__ short xh[2][BTOK][STR], xm_[2][BTOK][STR], xl_[2][BTOK][STR];
  __shared__ short wh[2][NE][STR],  wm_[2][NE][STR],  wl_[2][NE][STR];
  __shared__ float logits[BTOK][LSTRF];

  const int t    = threadIdx.x;
  const int lane = t & 63;
  const int wid  = t >> 6;            // 2 waves: expert halves
  const int tok0 = blockIdx.x * BTOK;

  // staging geometry
  const int xr = t >> 2, xk = (t & 3) << 3;   // x: row 0..31, 8 floats
  const int wr = t >> 1, wk = (t & 1) << 4;   // W: row 0..63, 16 floats
  const float* xg = x + (size_t)(tok0 + xr) * DM + xk;
  const float* wg = W + (size_t)wr * DM + wk;

  float4 gx0, gx1, gw0, gw1, gw2, gw3;

#define LOADX(c) { const float* _g = xg + (c) * BK; \
  gx0 = *(const float4*)_g; gx1 = *(const float4*)(_g + 4); }
#define LOADW(c) { const float* _g = wg + (c) * BK; \
  gw0 = *(const float4*)_g;       gw1 = *(const float4*)(_g + 4); \
  gw2 = *(const float4*)(_g + 8); gw3 = *(const float4*)(_g + 12); }

#define CVT_WRITE(b) { \
  short8 H, M, L; \
  SPLIT(gx0.x, H[0], M[0], L[0]) SPLIT(gx0.y, H[1], M[1], L[1]) \
  SPLIT(gx0.z, H[2], M[2], L[2]) SPLIT(gx0.w, H[3], M[3], L[3]) \
  SPLIT(gx1.x, H[4], M[4], L[4]) SPLIT(gx1.y, H[5], M[5], L[5]) \
  SPLIT(gx1.z, H[6], M[6], L[6]) SPLIT(gx1.w, H[7], M[7], L[7]) \
  *(short8*)&xh[b][xr][xk] = H; *(short8*)&xm_[b][xr][xk] = M; \
  *(short8*)&xl_[b][xr][xk] = L; \
  SPLIT(gw0.x, H[0], M[0], L[0]) SPLIT(gw0.y, H[1], M[1], L[1]) \
  SPLIT(gw0.z, H[2], M[2], L[2]) SPLIT(gw0.w, H[3], M[3], L[3]) \
  SPLIT(gw1.x, H[4], M[4], L[4]) SPLIT(gw1.y, H[5], M[5], L[5]) \
  SPLIT(gw1.z, H[6], M[6], L[6]) SPLIT(gw1.w, H[7], M[7], L[7]) \
  *(short8*)&wh[b][wr][wk] = H; *(short8*)&wm_[b][wr][wk] = M; \
  *(short8*)&wl_[b][wr][wk] = L; \
  SPLIT(gw2.x, H[0], M[0], L[0]) SPLIT(gw2.y, H[1], M[1], L[1]) \
  SPLIT(gw2.z, H[2], M[2], L[2]) SPLIT(gw2.w, H[3], M[3], L[3]) \
  SPLIT(gw3.x, H[4], M[4], L[4]) SPLIT(gw3.y, H[5], M[5], L[5]) \
  SPLIT(gw3.z, H[6], M[6], L[6]) SPLIT(gw3.w, H[7], M[7], L[7]) \
  *(short8*)&wh[b][wr][wk + 8] = H; *(short8*)&wm_[b][wr][wk + 8] = M; \
  *(short8*)&wl_[b][wr][wk + 8] = L; }

  f32x16 acc0 = {}, acc1 = {}, acc2 = {};
  const int ra = lane & 31;            // A row (token) and B row (expert mod 32)
  const int eb = wid << 5;             // expert half base

  // one MFMA k-step: identical addressing for A and B frags -> any k-map
  // error inside the 16-wide group cancels (permutation-invariant dot).
#define KSTEP(b, ks) { \
  const int _ko = ((ks) << 4) + ((lane >> 5) << 3); \
  const short8 ah = *(const short8*)&xh[b][ra][_ko]; \
  const short8 am = *(const short8*)&xm_[b][ra][_ko]; \
  const short8 al = *(const short8*)&xl_[b][ra][_ko]; \
  const short8 bh = *(const short8*)&wh[b][eb + ra][_ko]; \
  const short8 bm = *(const short8*)&wm_[b][eb + ra][_ko]; \
  const short8 bl = *(const short8*)&wl_[b][eb + ra][_ko]; \
  acc0 = MFMA(ah, bh, acc0); \
  acc1 = MFMA(ah, bm, acc1); acc1 = MFMA(am, bh, acc1); \
  acc2 = MFMA(ah, bl, acc2); acc2 = MFMA(am, bm, acc2); acc2 = MFMA(al, bh, acc2); }

  // ---- pipeline: loads 1 chunk ahead; 1 barrier per chunk ----
  LOADX(0) LOADW(0)
  CVT_WRITE(0)
  LOADX(1) LOADW(1)
  __syncthreads();

  for (int c = 0; c < NCHK; ++c) {
    const int cur = c & 1;
    KSTEP(cur, 0)
    KSTEP(cur, 1)
    if (c + 1 < NCHK) {
      CVT_WRITE(cur ^ 1)                       // chunk c+1 (regs loaded last iter)
      if (c + 2 < NCHK) { LOADX(c + 2) LOADW(c + 2) }
    }
    __syncthreads();
  }

  // ---- epilogue: combine scale planes, logits -> LDS ----
  // C/D map (m74/m101-verified): col = lane&31, row = (i&3)+8*(i>>2)+4*(lane>>5)
#pragma unroll
  for (int i = 0; i < 16; ++i) {
    const float v = acc0[i] + acc1[i] * 0.00390625f + acc2[i] * 1.52587890625e-05f;
    const int row = (i & 3) + ((i >> 2) << 3) + ((lane >> 5) << 2);
    logits[row][eb + ra] = v;
  }
  __syncthreads();

  // ---- top-8: wave wid handles 16 tokens; lane = expert (R8-validated) ----
#define PICK(p) { \
  float m = v; \
  m = fmaxf(m, __shfl_xor(m, 32)); \
  m = fmaxf(m, __shfl_xor(m, 16)); \
  m = fmaxf(m, __shfl_xor(m, 8));  \
  m = fmaxf(m, __shfl_xor(m, 4));  \
  m = fmaxf(m, __shfl_xor(m, 2));  \
  m = fmaxf(m, __shfl_xor(m, 1));  \
  const unsigned long long bm = __ballot(v == m); \
  const int ii = (int)__builtin_ctzll(bm); \
  idx##p = ii; \
  v = (lane == ii) ? NEGINF : v; }

  for (int tt = 0; tt < 16; ++tt) {
    const int trow = wid * 16 + tt;
    float v = logits[trow][lane];
    int idx0, idx1, idx2, idx3, idx4, idx5, idx6, idx7;
    PICK(0) PICK(1) PICK(2) PICK(3) PICK(4) PICK(5) PICK(6) PICK(7)
    if (lane == 0) {
      int4* op = (int4*)(out + (size_t)(tok0 + trow) * TOPK);
      op[0] = make_int4(idx0, idx1, idx2, idx3);
      op[1] = make_int4(idx4, idx5, idx6, idx7);
    }
  }
}

extern "C" void kernel_launch(void* const* d_in, const int* in_sizes, int n_in,
                              void* d_out, int out_size, void* d_ws, size_t ws_size,
                              hipStream_t stream) {
  const float* x = (const float*)d_in[0];
  const float* W = (const float*)d_in[1];
  int* out = (int*)d_out;
  (void)in_sizes; (void)n_in; (void)out_size; (void)d_ws; (void)ws_size;

  dim3 grid(NT / BTOK);   // 512 blocks (2 per CU)
  dim3 block(128);        // 2 waves: expert halves of a 32x64 tile
  hipLaunchKernelGGL(gate_kernel, grid, block, 0, stream, x, W, out);
}

// Round 10
// 99.074 us; speedup vs baseline: 76.5590x; 1.9218x over previous
//
#include <hip/hip_runtime.h>

typedef _Float16 f16x8 __attribute__((ext_vector_type(8)));
typedef float f32x16 __attribute__((ext_vector_type(16)));

#define NT 16384
#define DM 4096
#define NE 64
#define TOPK 8
#define BTOK 32
#define BK 64
#define NCHK (DM / BK)      // 64
#define XPL 4096            // bytes / x plane: 8 kg * 32 tok * 16B cells
#define XSZ (2 * XPL)
#define WPL 8192            // bytes / W plane: 8 kg * 64 e * 16B cells
#define WSZ (2 * WPL)
#define BUFSZ (XSZ + WSZ)   // 24576
#define SMEM_BYTES (2 * BUFSZ)
#define RSCALE 4.8828125e-4f   // 2^-11
#define NEGINF (-3.402823466e38f)

#define MF(a, b, c) __builtin_amdgcn_mfma_f32_32x32x16_f16((a), (b), (c), 0, 0, 0)

// v = h + l*2^-11 + rho, |rho| <= 2^-22 |v| (h cast RN, residual exact, l RN)
#define SP(V, H, L, j) { const float _v = (V); const _Float16 _h = (_Float16)_v; \
  H[j] = _h; L[j] = (_Float16)((_v - (float)_h) * 2048.0f); }
#define SPLIT8(F0, F1, H, L) { \
  SP(F0.x, H, L, 0) SP(F0.y, H, L, 1) SP(F0.z, H, L, 2) SP(F0.w, H, L, 3) \
  SP(F1.x, H, L, 4) SP(F1.y, H, L, 5) SP(F1.z, H, L, 6) SP(F1.w, H, L, 7) }

// ---------- pre-kernel: split W into 2 fp16 planes, rotated-cell layout ----------
__global__ __launch_bounds__(256) void wsplit_kernel(const float* __restrict__ W,
                                                     _Float16* __restrict__ wsp) {
  const int id = blockIdx.x * 256 + (int)threadIdx.x;   // 0..32767
  const int e = id >> 9, kgg = id & 511;
  const float* src = W + (size_t)e * DM + kgg * 8;
  const float4 a = ((const float4*)src)[0];
  const float4 b = ((const float4*)src)[1];
  f16x8 H, L; SPLIT8(a, b, H, L)
  const int c = kgg >> 3, kg = kgg & 7;
  const int cell = kg * 64 + ((e + kg) & 63);           // rotation: bank-uniform
  *(f16x8*)(wsp + ((size_t)(c * 2) * 512 + cell) * 8) = H;
  *(f16x8*)(wsp + ((size_t)(c * 2 + 1) * 512 + cell) * 8) = L;
}

// ---------- main kernel ----------
template<bool PRE>
__global__ __launch_bounds__(256, 2) void gate_kernel(
    const float* __restrict__ x, const float* __restrict__ W,
    const _Float16* __restrict__ wsp, int* __restrict__ out) {
  extern __shared__ char smem[];
  const int t = (int)threadIdx.x;
  const int lane = t & 63;
  const int w = t >> 6;                 // 4 waves
  const int et = w & 1, kh = w >> 1;    // expert half, K half
  const int l31 = lane & 31, lhi = lane >> 5;
  const int kh4 = kh * 4;
  const int ecol = et * 32 + l31;
  const int tok0 = blockIdx.x * BTOK;

  // x staging: thread -> (tok = t>>3, kg = t&7), 8 floats (256B runs, coalesced)
  const int sxtok = t >> 3, sxkg = t & 7;
  const float* xg = x + (size_t)(tok0 + sxtok) * DM + sxkg * 8;
  const int xoff0 = (sxkg * 32 + ((sxtok + sxkg) & 31)) * 16;

  // W fallback staging: thread -> (e = t>>2, kg0 = 2*(t&3)), 16 floats
  const int swe = t >> 2, swkg = (t & 3) << 1;
  const float* wg = W + (size_t)swe * DM + swkg * 8;
  const int woffA = ((swkg    ) * 64 + ((swe + swkg    ) & 63)) * 16;
  const int woffB = ((swkg + 1) * 64 + ((swe + swkg + 1) & 63)) * 16;

  f32x16 acc0 = {}, acc1 = {};
  float4 xr0, xr1, wr0, wr1, wr2, wr3;
  f16x8 pw00, pw01, pw10, pw11;

#define LOADX(c) { const float* _s = xg + (c) * BK; \
  xr0 = *(const float4*)_s; xr1 = *(const float4*)(_s + 4); }
#define LOADW_F(c) { const float* _s = wg + (c) * BK; \
  wr0 = ((const float4*)_s)[0]; wr1 = ((const float4*)_s)[1]; \
  wr2 = ((const float4*)_s)[2]; wr3 = ((const float4*)_s)[3]; }
#define LOADW_P(c) { const _Float16* _q = wsp + (size_t)(c) * 1024 * 8; \
  pw00 = *(const f16x8*)(_q + (size_t)t * 8); \
  pw01 = *(const f16x8*)(_q + (size_t)(256 + t) * 8); \
  pw10 = *(const f16x8*)(_q + (size_t)(512 + t) * 8); \
  pw11 = *(const f16x8*)(_q + (size_t)(768 + t) * 8); }

#define WRX(bn) { \
  f16x8 XH, XL; SPLIT8(xr0, xr1, XH, XL) \
  char* _b = smem + (bn) * BUFSZ; \
  *(f16x8*)(_b + xoff0) = XH; \
  *(f16x8*)(_b + XPL + xoff0) = XL; }
#define WRW_F(bn) { \
  f16x8 H0, L0, H1, L1; SPLIT8(wr0, wr1, H0, L0) SPLIT8(wr2, wr3, H1, L1) \
  char* _b = smem + (bn) * BUFSZ + XSZ; \
  *(f16x8*)(_b + woffA) = H0; *(f16x8*)(_b + WPL + woffA) = L0; \
  *(f16x8*)(_b + woffB) = H1; *(f16x8*)(_b + WPL + woffB) = L1; }
#define WRW_P(bn) { \
  char* _b = smem + (bn) * BUFSZ + XSZ; \
  *(f16x8*)(_b + t * 16) = pw00; \
  *(f16x8*)(_b + (256 + t) * 16) = pw01; \
  *(f16x8*)(_b + WPL + t * 16) = pw10; \
  *(f16x8*)(_b + WPL + (256 + t) * 16) = pw11; }

  // A and B use IDENTICAL slot->k mapping (R9-validated): k-map errors cancel.
#define KSTEP(bn, ks) { \
  const int _kg = kh4 + (ks) * 2 + lhi; \
  const char* _b = smem + (bn) * BUFSZ; \
  const int _ao = (_kg * 32 + ((l31 + _kg) & 31)) * 16; \
  const int _bo = (_kg * 64 + ((ecol + _kg) & 63)) * 16; \
  const f16x8 ah = *(const f16x8*)(_b + _ao); \
  const f16x8 al = *(const f16x8*)(_b + XPL + _ao); \
  const f16x8 bh = *(const f16x8*)(_b + XSZ + _bo); \
  const f16x8 bl = *(const f16x8*)(_b + XSZ + WPL + _bo); \
  acc0 = MF(ah, bh, acc0); \
  acc1 = MF(ah, bl, acc1); \
  acc1 = MF(al, bh, acc1); }

  // ---- prologue: stage chunk 0 ----
  LOADX(0)
  if (PRE) { LOADW_P(0) } else { LOADW_F(0) }
  WRX(0)
  if (PRE) { WRW_P(0) } else { WRW_F(0) }
  __syncthreads();

  // ---- main loop: loads at TOP (in flight across MFMAs), 1 barrier/chunk ----
  for (int c = 0; c < NCHK; ++c) {
    const int bn = c & 1;
    if (c + 1 < NCHK) {
      LOADX(c + 1)
      if (PRE) { LOADW_P(c + 1) } else { LOADW_F(c + 1) }
    }
    KSTEP(bn, 0)
    KSTEP(bn, 1)
    if (c + 1 < NCHK) {
      WRX(bn ^ 1)
      if (PRE) { WRW_P(bn ^ 1) } else { WRW_F(bn ^ 1) }
    }
    __syncthreads();
  }

  // ---- merge K halves, build logits[32][68] (staging LDS reused) ----
  float* mg = (float*)smem;                // 8 KB merge area
  float* lg = (float*)(smem + 8192);       // 32*68*4 = 8704 B
  if (kh == 1) {
#pragma unroll 16
    for (int i = 0; i < 16; ++i)
      mg[et * 1024 + i * 64 + lane] = acc0[i] + acc1[i] * RSCALE;
  }
  __syncthreads();
  if (kh == 0) {
#pragma unroll 16
    for (int i = 0; i < 16; ++i) {
      const float v = acc0[i] + acc1[i] * RSCALE + mg[et * 1024 + i * 64 + lane];
      const int row = (i & 3) + ((i >> 2) << 3) + (lhi << 2);  // m74/m101-verified
      lg[row * 68 + ecol] = v;
    }
  }
  __syncthreads();

  // ---- top-8 per token: lane = expert, ballot-argmax (R8/R9-validated) ----
#define PICK(p) { \
  float m = v; \
  m = fmaxf(m, __shfl_xor(m, 32)); \
  m = fmaxf(m, __shfl_xor(m, 16)); \
  m = fmaxf(m, __shfl_xor(m, 8));  \
  m = fmaxf(m, __shfl_xor(m, 4));  \
  m = fmaxf(m, __shfl_xor(m, 2));  \
  m = fmaxf(m, __shfl_xor(m, 1));  \
  const unsigned long long bm = __ballot(v == m); \
  const int ii = (int)__builtin_ctzll(bm); \
  idx##p = ii; \
  v = (lane == ii) ? NEGINF : v; }

  for (int tt = 0; tt < 8; ++tt) {
    const int trow = w * 8 + tt;
    float v = lg[trow * 68 + lane];
    int idx0, idx1, idx2, idx3, idx4, idx5, idx6, idx7;
    PICK(0) PICK(1) PICK(2) PICK(3) PICK(4) PICK(5) PICK(6) PICK(7)
    if (lane == 0) {
      int4* op = (int4*)(out + (size_t)(tok0 + trow) * TOPK);
      op[0] = make_int4(idx0, idx1, idx2, idx3);
      op[1] = make_int4(idx4, idx5, idx6, idx7);
    }
  }
}

extern "C" void kernel_launch(void* const* d_in, const int* in_sizes, int n_in,
                              void* d_out, int out_size, void* d_ws, size_t ws_size,
                              hipStream_t stream) {
  const float* x = (const float*)d_in[0];
  const float* W = (const float*)d_in[1];
  int* out = (int*)d_out;
  (void)in_sizes; (void)n_in; (void)out_size;

  const size_t need = (size_t)NE * DM * 2 * sizeof(_Float16);  // 1 MB
  if (ws_size >= need && d_ws != nullptr) {
    _Float16* wsp = (_Float16*)d_ws;
    hipLaunchKernelGGL(wsplit_kernel, dim3(128), dim3(256), 0, stream, W, wsp);
    hipLaunchKernelGGL((gate_kernel<true>), dim3(NT / BTOK), dim3(256),
                       SMEM_BYTES, stream, x, W, (const _Float16*)wsp, out);
  } else {
    hipLaunchKernelGGL((gate_kernel<false>), dim3(NT / BTOK), dim3(256),
                       SMEM_BYTES, stream, x, W, (const _Float16*)nullptr, out);
  }
}

// Round 11
// 90.728 us; speedup vs baseline: 83.6013x; 1.0920x over previous
//
#include <hip/hip_runtime.h>

typedef _Float16 f16x8 __attribute__((ext_vector_type(8)));
typedef float f32x16 __attribute__((ext_vector_type(16)));

#define NT 16384
#define DM 4096
#define NE 64
#define TOPK 8
#define BTOK 32
#define BK 64
#define NCHK (DM / BK)         // 64
#define XPL 4096               // bytes per x plane in LDS (8 kg * 32 cells * 16B)
#define RSCALE 4.8828125e-4f   // 2^-11
#define NEGINF (-3.402823466e38f)

#define MF(a, b, c) __builtin_amdgcn_mfma_f32_32x32x16_f16((a), (b), (c), 0, 0, 0)

// v = h + l*2^-11 + rho, |rho| <= 2^-22 |v|
#define SP(V, H, L, j) { const float _v = (V); const _Float16 _h = (_Float16)_v; \
  H[j] = _h; L[j] = (_Float16)((_v - (float)_h) * 2048.0f); }
#define SPLIT8(F0, F1, H, L) { \
  SP(F0.x, H, L, 0) SP(F0.y, H, L, 1) SP(F0.z, H, L, 2) SP(F0.w, H, L, 3) \
  SP(F1.x, H, L, 4) SP(F1.y, H, L, 5) SP(F1.z, H, L, 6) SP(F1.w, H, L, 7) }

// ---------- pre-kernel: split W into 2 fp16 planes, LINEAR chunk layout ----------
// wsp elem ((c*2 + p)*512 + kg*64 + e)*8 + j  <->  W[e][c*64 + kg*8 + j], plane p
__global__ __launch_bounds__(256) void wsplit_kernel(const float* __restrict__ W,
                                                     _Float16* __restrict__ wsp) {
  const int id = blockIdx.x * 256 + (int)threadIdx.x;   // 0..32767
  const int e = id >> 9, kgg = id & 511;
  const float* src = W + (size_t)e * DM + kgg * 8;
  const float4 a = ((const float4*)src)[0];
  const float4 b = ((const float4*)src)[1];
  f16x8 H, L; SPLIT8(a, b, H, L)
  const int c = kgg >> 3, kg = kgg & 7;
  *(f16x8*)(wsp + ((size_t)(c * 2) * 512 + kg * 64 + e) * 8) = H;
  *(f16x8*)(wsp + ((size_t)(c * 2 + 1) * 512 + kg * 64 + e) * 8) = L;
}

// ---------- main kernel ----------
template<bool PRE>
__global__ __launch_bounds__(256, 2) void gate_kernel(
    const float* __restrict__ x, const float* __restrict__ W,
    const _Float16* __restrict__ wsp, int* __restrict__ out) {

  __shared__ __align__(16) char xsmem[2][2 * XPL];   // x only: 16 KB
  __shared__ float lg[BTOK][68];

  const int t = (int)threadIdx.x;
  const int lane = t & 63;
  const int w = t >> 6;                 // 4 waves
  const int et = w & 1, kh = w >> 1;    // expert half, K half
  const int l31 = lane & 31, lhi = lane >> 5;
  const int kh4 = kh * 4;
  const int ecol = et * 32 + l31;
  const int tok0 = blockIdx.x * BTOK;

  // x staging: thread -> (tok = t>>3, kg = t&7), 8 floats (256B runs, coalesced)
  const int sxtok = t >> 3, sxkg = t & 7;
  const float* xg = x + (size_t)(tok0 + sxtok) * DM + sxkg * 8;
  const int xoff0 = (sxkg * 32 + ((sxtok + sxkg) & 31)) * 16;   // rotated cells

  // B direct-load base (PRE): lane -> cell (kg, ecol); per half-wave 512B runs
  const _Float16* wb = PRE ? (wsp + ((size_t)(kh4 + lhi) * 64 + ecol) * 8) : nullptr;
  // B fallback base (fp32 W, perf-irrelevant)
  const float* wf = W + (size_t)ecol * DM + (kh4 + lhi) * 8;

  f32x16 acc0 = {}, acc1 = {}, acc2 = {};

  float4 XA0, XA1, XB0, XB1;
  f16x8 B0h0, B0l0, B0h1, B0l1, B1h0, B1l0, B1h1, B1l1;

#define LOADX(c, Xp) { const float* _s = xg + (c) * BK; \
  Xp##0 = *(const float4*)_s; Xp##1 = *(const float4*)(_s + 4); }

#define LOADB(c, Bp) { \
  if (PRE) { \
    const _Float16* _q = wb + (size_t)(c) * 8192; \
    Bp##h0 = *(const f16x8*)(_q);         /* plane h, ks=0 */ \
    Bp##h1 = *(const f16x8*)(_q + 1024);  /* kg+2 */ \
    Bp##l0 = *(const f16x8*)(_q + 4096); \
    Bp##l1 = *(const f16x8*)(_q + 5120); \
  } else { \
    const float* _p = wf + (size_t)(c) * BK; \
    const float4 _a0 = ((const float4*)_p)[0], _a1 = ((const float4*)_p)[1]; \
    const float4 _b0 = ((const float4*)(_p + 16))[0], _b1 = ((const float4*)(_p + 16))[1]; \
    SPLIT8(_a0, _a1, Bp##h0, Bp##l0) \
    SPLIT8(_b0, _b1, Bp##h1, Bp##l1) \
  } }

#define WRX(bn, Xp) { \
  f16x8 XH, XL; SPLIT8(Xp##0, Xp##1, XH, XL) \
  char* _b = xsmem[bn]; \
  *(f16x8*)(_b + xoff0) = XH; \
  *(f16x8*)(_b + XPL + xoff0) = XL; }

  // A and B use IDENTICAL (lhi,slot)->k mapping (R9/R10-validated: k-map
  // errors cancel; C/D map is the verified one).
#define KSTEP(bn, Bp, ks) { \
  const int _kg = kh4 + (ks) * 2 + lhi; \
  const int _ao = (_kg * 32 + ((l31 + _kg) & 31)) * 16; \
  const char* _b = xsmem[bn]; \
  const f16x8 ah = *(const f16x8*)(_b + _ao); \
  const f16x8 al = *(const f16x8*)(_b + XPL + _ao); \
  acc0 = MF(ah, Bp##h##ks, acc0); \
  acc1 = MF(ah, Bp##l##ks, acc1); \
  acc2 = MF(al, Bp##h##ks, acc2); }

#define BODY(c, Xw, Xl, Bc, Bn) { \
  if ((c) + 2 < NCHK) LOADX((c) + 2, Xl) \
  if ((c) + 1 < NCHK) LOADB((c) + 1, Bn) \
  KSTEP((c) & 1, Bc, 0) \
  KSTEP((c) & 1, Bc, 1) \
  if ((c) + 1 < NCHK) WRX(((c) + 1) & 1, Xw) \
  __syncthreads(); }

  // ---- prologue ----
  LOADX(0, XA)
  WRX(0, XA)
  LOADB(0, B0)
  LOADX(1, XA)
  __syncthreads();

  // ---- main loop: 2 chunks per iteration (static reg ping-pong) ----
  for (int c = 0; c < NCHK; c += 2) {
    BODY(c,     XA, XB, B0, B1)
    BODY(c + 1, XB, XA, B1, B0)
  }

  // ---- merge K halves (reuse xsmem[0]: 8 KB), build logits ----
  float* mg = (float*)xsmem[0];
  if (kh == 1) {
#pragma unroll 16
    for (int i = 0; i < 16; ++i)
      mg[et * 1024 + i * 64 + lane] = acc0[i] + (acc1[i] + acc2[i]) * RSCALE;
  }
  __syncthreads();
  if (kh == 0) {
#pragma unroll 16
    for (int i = 0; i < 16; ++i) {
      const float v = acc0[i] + (acc1[i] + acc2[i]) * RSCALE
                    + mg[et * 1024 + i * 64 + lane];
      const int row = (i & 3) + ((i >> 2) << 3) + (lhi << 2);  // verified C/D map
      lg[row][ecol] = v;
    }
  }
  __syncthreads();

  // ---- top-8 per token: lane = expert, ballot-argmax (R8-R10 validated) ----
#define PICK(p) { \
  float m = v; \
  m = fmaxf(m, __shfl_xor(m, 32)); \
  m = fmaxf(m, __shfl_xor(m, 16)); \
  m = fmaxf(m, __shfl_xor(m, 8));  \
  m = fmaxf(m, __shfl_xor(m, 4));  \
  m = fmaxf(m, __shfl_xor(m, 2));  \
  m = fmaxf(m, __shfl_xor(m, 1));  \
  const unsigned long long bm = __ballot(v == m); \
  const int ii = (int)__builtin_ctzll(bm); \
  idx##p = ii; \
  v = (lane == ii) ? NEGINF : v; }

  for (int tt = 0; tt < 8; ++tt) {
    const int trow = w * 8 + tt;
    float v = lg[trow][lane];
    int idx0, idx1, idx2, idx3, idx4, idx5, idx6, idx7;
    PICK(0) PICK(1) PICK(2) PICK(3) PICK(4) PICK(5) PICK(6) PICK(7)
    if (lane == 0) {
      int4* op = (int4*)(out + (size_t)(tok0 + trow) * TOPK);
      op[0] = make_int4(idx0, idx1, idx2, idx3);
      op[1] = make_int4(idx4, idx5, idx6, idx7);
    }
  }
}

extern "C" void kernel_launch(void* const* d_in, const int* in_sizes, int n_in,
                              void* d_out, int out_size, void* d_ws, size_t ws_size,
                              hipStream_t stream) {
  const float* x = (const float*)d_in[0];
  const float* W = (const float*)d_in[1];
  int* out = (int*)d_out;
  (void)in_sizes; (void)n_in; (void)out_size;

  const size_t need = (size_t)NE * DM * 2 * sizeof(_Float16);  // 1 MB
  if (ws_size >= need && d_ws != nullptr) {
    _Float16* wsp = (_Float16*)d_ws;
    hipLaunchKernelGGL(wsplit_kernel, dim3(128), dim3(256), 0, stream, W, wsp);
    hipLaunchKernelGGL((gate_kernel<true>), dim3(NT / BTOK), dim3(256),
                       0, stream, x, W, (const _Float16*)wsp, out);
  } else {
    hipLaunchKernelGGL((gate_kernel<false>), dim3(NT / BTOK), dim3(256),
                       0, stream, x, W, (const _Float16*)nullptr, out);
  }
}